// Round 3
// baseline (2280.134 us; speedup 1.0000x reference)
//
#include <hip/hip_runtime.h>

// Sizes (fixed by the problem)
#define DZc 512
#define Bc  64
#define Tc  1000
#define DUc 16
#define DXc 256

#define KTOT 17            // 16 W k-tiles + 1 augmented (Wu, v hi/lo) tile
#define NFRAG (KTOT * 4)   // 68 fragments per wave (4 n-tiles each)
#define NREG  40           // frags in VGPR/AGPR (c = 0..39)
#define NLDS  12           // frags in LDS       (c = 40..51)
#define NSTR  16           // frags streamed L2  (c = 52..67, kt 13..16)
#define AROW  552          // padded activation row length (bf16 elems)

// Workspace layout:
//   Wp : bf16 augmented W' [544 k][512 n] in B-fragment order  278528 ushort
//   Bp : bf16 B_obs in B-fragment order                        131072 ushort
//   zs : bf16 z-history [T][B][DZ]                             32768000 ushort

typedef __attribute__((ext_vector_type(4))) float f32x4;
typedef __attribute__((ext_vector_type(8))) short s16x8;

__device__ __forceinline__ unsigned short f2bf(float x) {
  unsigned u = __builtin_bit_cast(unsigned, x);
  u = u + 0x7FFFu + ((u >> 16) & 1u);   // round-to-nearest-even
  return (unsigned short)(u >> 16);
}
__device__ __forceinline__ float bf2f(unsigned short u) {
  unsigned x = ((unsigned)u) << 16;
  return __builtin_bit_cast(float, x);
}

// Pack augmented W' into bf16 MFMA B-fragments.
// W'[n][k]: k<512 -> W[n][k]; k in [512,544) -> Wu[n][k&15].
// Fragment (kt,nt): lane l elem j holds B[k][n], n = nt*16+(l&15),
// k = kt*32+(l>>4)*8+j.  Linear: Wp[((kt*32+nt)*64+l)*8+j]
__global__ void pack_w_kernel(const float* __restrict__ W,
                              const float* __restrict__ Wu,
                              unsigned short* __restrict__ Wp) {
  int d = blockIdx.x * 256 + threadIdx.x;          // 278528 total
  int j = d & 7, l = (d >> 3) & 63, nt = (d >> 9) & 31, kt = d >> 14;
  int n = nt * 16 + (l & 15);
  int k = kt * 32 + ((l >> 4) << 3) + j;
  float val = (k < DZc) ? W[n * DZc + k] : Wu[n * DUc + (k & 15)];
  Wp[d] = f2bf(val);
}

// Pack B_obs[512][256] ([z][x]) into bf16 B-fragments: B[k][n] = B_obs[k][n].
__global__ void pack_b_kernel(const float* __restrict__ B,
                              unsigned short* __restrict__ Bp) {
  int d = blockIdx.x * 256 + threadIdx.x;          // 131072 total
  int j = d & 7, l = (d >> 3) & 63, nt = (d >> 9) & 15, kt = d >> 13;
  int n = nt * 16 + (l & 15);
  int k = kt * 32 + ((l >> 4) << 3) + j;
  Bp[d] = f2bf(B[k * DXc + n]);
}

// Recurrence: 4 WGs x 512 threads (8 waves), 16 trials each. W split:
// 40 frags/wave in regs, 12 in LDS, 16 streamed from L2 each step with
// 2-group prefetch lead. Double-buffered activation LDS, one raw
// (lgkmcnt-only) barrier per step so global ops stay in flight.
__global__ __launch_bounds__(512, 2) void rnn_rec_kernel(
    const float* __restrict__ z0, const float* __restrict__ v,
    const float* __restrict__ h, const float* __restrict__ dp,
    const unsigned short* __restrict__ Wp, unsigned short* __restrict__ zs) {
  __shared__ unsigned short wlds[8][NLDS][512];    // 96 KiB
  __shared__ unsigned short abuf[2][16][AROW];     // 34.5 KiB (double-buffered)

  const int tid = threadIdx.x;
  const int lane = tid & 63;
  const int w = tid >> 6;
  const int l15 = lane & 15;
  const int lg = lane >> 4;
  const int b0 = blockIdx.x * 16;

  // ---- one-time: W fragments into regs + LDS (c = 0..51) ----
  s16x8 wr[NREG];
#pragma unroll
  for (int c = 0; c < NREG + NLDS; ++c) {
    int kt = c >> 2, nt = c & 3;
    s16x8 f = *(const s16x8*)(Wp + ((size_t)((kt * 32 + w * 4 + nt) * 64 + lane)) * 8);
    if (c < NREG) wr[c] = f;
    else *(s16x8*)&wlds[w][c - NREG][lane * 8] = f;
  }
  // streamed-frag base for this wave (frag c: + (c>>2)*16384 + (c&3)*512)
  const unsigned short* ws_base = Wp + (size_t)(w * 4 * 512 + lane * 8);

  // ---- one-time: z0 into acc, h into regs ----
  float hreg[4];
  f32x4 acc[4];
#pragma unroll
  for (int nt = 0; nt < 4; ++nt) {
    hreg[nt] = h[w * 64 + nt * 16 + l15];
#pragma unroll
    for (int r = 0; r < 4; ++r)
      acc[nt][r] = z0[(size_t)(b0 + lg * 4 + r) * DZc + w * 64 + nt * 16 + l15];
  }
  const float decay = expf(-expf(dp[0]));

  // v staging: threads 0..255 each own one (trial, du) slot
  const int du = tid & 15, trr = tid >> 4;
  const size_t vbase = ((size_t)(b0 + trr) * DUc + du) * Tc;
  float vcur = (tid < 256) ? v[vbase] : 0.f;

  // initial activation + v0 into abuf[0]
#pragma unroll
  for (int nt = 0; nt < 4; ++nt)
#pragma unroll
    for (int r = 0; r < 4; ++r) {
      float av = acc[nt][r] - hreg[nt];
      abuf[0][lg * 4 + r][w * 64 + nt * 16 + l15] = f2bf(av > 0.f ? av : 0.f);
    }
  if (tid < 256) {
    unsigned short hi = f2bf(vcur);
    abuf[0][trr][512 + du] = hi;
    abuf[0][trr][528 + du] = f2bf(vcur - bf2f(hi));
  }

  // zs [t][b][dz]: base for (t=0, r=0, nt=0)
  unsigned short* zbase = zs + (size_t)(b0 + lg * 4) * DZc + w * 64 + l15;

  int opaque = 0;                                  // defeats LICM of W-stream
  int p = 0;
  for (int t = 0; t < Tc; ++t) {
    asm volatile("" : "+v"(opaque));
    const unsigned short* wsp = ws_base + opaque;

    // lgkmcnt-only barrier: LDS writes visible, global ops stay in flight
    asm volatile("s_waitcnt lgkmcnt(0)\n\ts_barrier" ::: "memory");

    // prefetch next step's v
    float vnext = (tid < 256) ? v[vbase + (t + 1 < Tc ? t + 1 : Tc - 1)] : 0.f;

#pragma unroll
    for (int nt = 0; nt < 4; ++nt)
#pragma unroll
      for (int r = 0; r < 4; ++r) acc[nt][r] *= decay;

    s16x8 sbuf[NSTR];
#pragma unroll
    for (int kt = 0; kt < KTOT; ++kt) {
      // issue L2-stream loads for group kt+2 (kt_c in [13,16])
#pragma unroll
      for (int c = NREG + NLDS; c < NFRAG; ++c)
        if ((c >> 2) == kt + 2)
          sbuf[c - NREG - NLDS] =
              *(const s16x8*)(wsp + (size_t)(c >> 2) * 16384 + (c & 3) * 512);

      s16x8 af = *(const s16x8*)&abuf[p][l15][kt * 32 + lg * 8];
#pragma unroll
      for (int nt = 0; nt < 4; ++nt) {
        int c = kt * 4 + nt;
        s16x8 bf = (c < NREG) ? wr[c]
                 : (c < NREG + NLDS) ? *(const s16x8*)&wlds[w][c - NREG][lane * 8]
                 : sbuf[c - NREG - NLDS];
        acc[nt] = __builtin_amdgcn_mfma_f32_16x16x32_bf16(af, bf, acc[nt], 0, 0, 0);
      }
    }

    // store z_{t+1} to zs[t][b][dz] (fire-and-forget, crosses the barrier)
#pragma unroll
    for (int nt = 0; nt < 4; ++nt)
#pragma unroll
      for (int r = 0; r < 4; ++r)
        zbase[r * DZc + nt * 16] = f2bf(acc[nt][r]);
    zbase += Bc * DZc;

    // write phase: a(t+1) + v(t+1) into the other buffer (no barrier needed:
    // all waves finished reading buf p^1 before the barrier at step t)
#pragma unroll
    for (int nt = 0; nt < 4; ++nt)
#pragma unroll
      for (int r = 0; r < 4; ++r) {
        float av = acc[nt][r] - hreg[nt];
        abuf[p ^ 1][lg * 4 + r][w * 64 + nt * 16 + l15] = f2bf(av > 0.f ? av : 0.f);
      }
    if (tid < 256) {
      unsigned short hi = f2bf(vnext);
      abuf[p ^ 1][trr][512 + du] = hi;
      abuf[p ^ 1][trr][528 + du] = f2bf(vnext - bf2f(hi));
    }
    p ^= 1;
    vcur = vnext;
  }
}

// Projection: x[b][xo][t] = sum_z B_obs[z][xo] * zs[t][b][z] + Bias[xo].
// One WG (256 thr = 4 waves) per (b, 16-t tile); 63 tiles (last masked).
__global__ __launch_bounds__(256, 1) void rnn_proj_kernel(
    const unsigned short* __restrict__ zs, const unsigned short* __restrict__ Bp,
    const float* __restrict__ Bias, float* __restrict__ x) {
  const int wg = blockIdx.x;                       // 64*63 = 4032
  const int b = wg / 63;
  const int tbase = (wg % 63) * 16;
  const int tid = threadIdx.x;
  const int lane = tid & 63;
  const int w = tid >> 6;
  const int l15 = lane & 15, lg = lane >> 4;

  const int trow = tbase + l15;
  const int trc = trow < Tc ? trow : Tc - 1;
  const unsigned short* abase = zs + ((size_t)trc * Bc + b) * DZc + lg * 8;
  const s16x8 zz = {0, 0, 0, 0, 0, 0, 0, 0};

  f32x4 acc[4];
#pragma unroll
  for (int n = 0; n < 4; ++n)
#pragma unroll
    for (int e = 0; e < 4; ++e) acc[n][e] = 0.f;

#pragma unroll
  for (int kt = 0; kt < 16; ++kt) {
    s16x8 af = *(const s16x8*)(abase + kt * 32);
    af = (trow < Tc) ? af : zz;                    // mask pad t-rows
#pragma unroll
    for (int n = 0; n < 4; ++n) {
      s16x8 bf = *(const s16x8*)(Bp + (size_t)((kt * 16 + w * 4 + n) * 64 + lane) * 8);
      acc[n] = __builtin_amdgcn_mfma_f32_16x16x32_bf16(af, bf, acc[n], 0, 0, 0);
    }
  }

  const int t = tbase + lg * 4;                    // regs cover t..t+3
  if (t < Tc) {
#pragma unroll
    for (int n = 0; n < 4; ++n) {
      int xo = (w * 4 + n) * 16 + l15;
      float bias = Bias[xo];
      f32x4 val = acc[n];
#pragma unroll
      for (int e = 0; e < 4; ++e) val[e] += bias;
      *(f32x4*)(x + ((size_t)b * DXc + xo) * Tc + t) = val;
    }
  }
}

extern "C" void kernel_launch(void* const* d_in, const int* in_sizes, int n_in,
                              void* d_out, int out_size, void* d_ws, size_t ws_size,
                              hipStream_t stream) {
  const float* z0   = (const float*)d_in[0];
  const float* v    = (const float*)d_in[1];
  const float* W    = (const float*)d_in[2];
  const float* Wu   = (const float*)d_in[3];
  const float* h    = (const float*)d_in[4];
  const float* dp   = (const float*)d_in[5];
  const float* Bo   = (const float*)d_in[6];
  const float* Bias = (const float*)d_in[7];
  float* x = (float*)d_out;

  unsigned short* Wp = (unsigned short*)d_ws;          // 278528 ushort
  unsigned short* Bp = Wp + 278528;                    // 131072 ushort
  unsigned short* zs = Bp + 131072;                    // 1000*64*512 ushort

  pack_w_kernel<<<1088, 256, 0, stream>>>(W, Wu, Wp);
  pack_b_kernel<<<512, 256, 0, stream>>>(Bo, Bp);
  rnn_rec_kernel<<<4, 512, 0, stream>>>(z0, v, h, dp, Wp, zs);
  rnn_proj_kernel<<<4032, 256, 0, stream>>>(zs, Bp, Bias, x);
}